// Round 10
// baseline (21933.075 us; speedup 1.0000x reference)
//
#include <hip/hip_runtime.h>

#define TSEQ 8192
#define DH   2048
#define DCAT 4096
#define ROWS 8      // rows per WG in fallback kernel
#define RPW  16     // rows per WG in main seq kernel (one per wave)
#define NWG  (DH / RPW)   // 128
#define R3   32     // time rows per MFMA workgroup

typedef __attribute__((ext_vector_type(8))) short bf16x8;
typedef __attribute__((ext_vector_type(4))) float f32x4;

__device__ inline short f2bf(float f) {  // RNE float->bf16
  unsigned int u = __float_as_uint(f);
  unsigned int r = (u + 0x7fffu + ((u >> 16) & 1u)) >> 16;
  return (short)r;
}

// granule (16B) swizzle for the LDS h buffer; MUST be used on both the
// write and the read side (both-sides-or-neither).
__device__ inline int swzg(int g) { return g ^ ((g >> 3) & 7); }

// ---------------------------------------------------------------------------
// Kernel 1: sentinel-init rows 1..8191 of d_out (h exchange buffer).
// Valid h values are sigmoid outputs (sign bit 0); sentinel -1.0f has sign 1.
// Runs every launch (harness does not re-poison between replays).
// ---------------------------------------------------------------------------
__global__ void init_sentinel_kernel(float* __restrict__ out) {
  const long long n4 = ((long long)(TSEQ - 1) * DH) / 4;  // rows 1..8191
  float4* p = (float4*)(out + DH);
  float4 s;
  s.x = s.y = s.z = s.w = -1.0f;
  const long long stride = (long long)gridDim.x * blockDim.x;
  for (long long i = (long long)blockIdx.x * blockDim.x + threadIdx.x; i < n4;
       i += stride)
    p[i] = s;
}

// ---------------------------------------------------------------------------
// Kernel 2a: zx precompute (batch GEMM, MFMA): zx[t] = W_hx·caption[t-1]+b_h
// for t=1..8191, stored in d_ws. Verified template (rounds 4-9).
// ---------------------------------------------------------------------------
__global__ __launch_bounds__(256, 1) void zx_mfma_kernel(
    float* __restrict__ zx, const float* __restrict__ caption,
    const float* __restrict__ W_h, const float* __restrict__ b_h) {
  __shared__ __align__(16) short hs[R3 * 2048];  // exactly 128 KiB
  const int tid  = threadIdx.x;
  const int lane = tid & 63;
  const int wv   = tid >> 6;
  const long long ct0 = (long long)blockIdx.x * R3;  // caption row base
  const int r16  = lane & 15;
  const int kgrp = (lane >> 4) * 8;

  for (int idx = tid; idx < R3 * 256; idx += 256) {
    const int row = idx >> 8;
    const int c8  = idx & 255;
    const float* src = caption + (ct0 + row) * DH + c8 * 8;
    float4 va = *(const float4*)src;
    float4 vb = *(const float4*)(src + 4);
    bf16x8 h8;
    h8[0] = f2bf(va.x); h8[1] = f2bf(va.y); h8[2] = f2bf(va.z); h8[3] = f2bf(va.w);
    h8[4] = f2bf(vb.x); h8[5] = f2bf(vb.y); h8[6] = f2bf(vb.z); h8[7] = f2bf(vb.w);
    *(bf16x8*)&hs[row * 2048 + ((c8 * 8) ^ ((row & 7) << 3))] = h8;
  }
  __syncthreads();

  const int sw0 = (r16 & 7) << 3;

  for (int half = 0; half < 4; ++half) {
    const int n0 = wv * 512 + half * 128;
    f32x4 acc0[8], acc1[8];
#pragma unroll
    for (int j = 0; j < 8; ++j) {
      acc0[j] = (f32x4){0.f, 0.f, 0.f, 0.f};
      acc1[j] = (f32x4){0.f, 0.f, 0.f, 0.f};
    }
    for (int k0 = 0; k0 < DH; k0 += 32) {
      const int kofs = (k0 + kgrp) ^ sw0;
      bf16x8 a0 = *(const bf16x8*)&hs[r16 * 2048 + kofs];
      bf16x8 a1 = *(const bf16x8*)&hs[(16 + r16) * 2048 + kofs];
#pragma unroll
      for (int j = 0; j < 8; ++j) {
        const float* wp =
            W_h + (long long)(n0 + j * 16 + r16) * DCAT + k0 + kgrp;  // x half
        float4 wa = *(const float4*)wp;
        float4 wb = *(const float4*)(wp + 4);
        bf16x8 bfr;
        bfr[0] = f2bf(wa.x); bfr[1] = f2bf(wa.y);
        bfr[2] = f2bf(wa.z); bfr[3] = f2bf(wa.w);
        bfr[4] = f2bf(wb.x); bfr[5] = f2bf(wb.y);
        bfr[6] = f2bf(wb.z); bfr[7] = f2bf(wb.w);
        acc0[j] = __builtin_amdgcn_mfma_f32_16x16x32_bf16(a0, bfr, acc0[j], 0, 0, 0);
        acc1[j] = __builtin_amdgcn_mfma_f32_16x16x32_bf16(a1, bfr, acc1[j], 0, 0, 0);
      }
    }
#pragma unroll
    for (int j = 0; j < 8; ++j) {
      const int n = n0 + j * 16 + r16;
      const float bh = b_h[n];
#pragma unroll
      for (int r = 0; r < 4; ++r) {
        const long long z0 = ct0 + (lane >> 4) * 4 + r + 1;   // z row = cap row + 1
        if (z0 < TSEQ) zx[z0 * DH + n] = acc0[j][r] + bh;
        const long long z1 = ct0 + 16 + (lane >> 4) * 4 + r + 1;
        if (z1 < TSEQ) zx[z1 * DH + n] = acc1[j][r] + bh;
      }
    }
  }
}

// ---------------------------------------------------------------------------
// Kernel 2b: persistent sequential RNN, row-per-wave. 128 WGs x 1024 thr.
// WG g owns rows [16g,16g+16); wave w computes row 16g+w alone: lane holds
// cols 32*lane..+32 of that W_hh row in 32 pinned VGPRs; reduction is six
// plain shfl_xor stages; lane 0 adds zx (depth-2 FIFO), sigmoid, publishes.
// There is NO second-level reduction, NO red LDS, NO tail wave (r9's chain
// spent ~1/2 its time there).
// Exchange: only waves 0,1 poll (lane: 8 coalesced u64 agent loads of its
// 16 h columns, sign-bit sentinel, s_sleep throttle) -> system poll traffic
// halves and 14/16 waves issue nothing while waiting. Pollers write h into
// LDS hb[t&1] with granule swizzle swzg on write AND read (conflict-optimal
// for b128 on both sides). One __syncthreads per step.
// Buffer safety: hb[t&1] rewritten at t+2 only after barrier(t+1), which
// requires every wave's hb[t&1] read (step t) to have completed: wave reads
// hb before its publish(t), publish(t) precedes its barrier(t+1) arrival.
// Race-ahead: a poller reaches spin(t+2) only after h[t+1] complete, which
// needs every WG's publishes at t+1, which follow their hb reads at t+1.
// ---------------------------------------------------------------------------
__global__ __launch_bounds__(1024, 1) void seq_kernel(
    const float* __restrict__ features, const float* __restrict__ zx,
    const float* __restrict__ W_h, float* __restrict__ out) {
  const int tid  = threadIdx.x;
  const int lane = tid & 63;
  const int w    = tid >> 6;          // wave 0..15
  const int row  = blockIdx.x * RPW + w;

  __shared__ float hb[2][2048];       // swizzled granules, 16 KiB

  // --- weights: lane holds cols 32*lane..+32 of W_hh[row]; pin in VGPRs ---
  float4 wr[8];
  {
    const float* wrow = W_h + (long long)row * DCAT + DH + 32 * lane;
#pragma unroll
    for (int k = 0; k < 8; ++k) wr[k] = *(const float4*)(wrow + 4 * k);
  }
  asm volatile("" : "+v"(wr[0].x), "+v"(wr[0].y), "+v"(wr[0].z), "+v"(wr[0].w),
                    "+v"(wr[1].x), "+v"(wr[1].y), "+v"(wr[1].z), "+v"(wr[1].w),
                    "+v"(wr[2].x), "+v"(wr[2].y), "+v"(wr[2].z), "+v"(wr[2].w),
                    "+v"(wr[3].x), "+v"(wr[3].y), "+v"(wr[3].z), "+v"(wr[3].w));
  asm volatile("" : "+v"(wr[4].x), "+v"(wr[4].y), "+v"(wr[4].z), "+v"(wr[4].w),
                    "+v"(wr[5].x), "+v"(wr[5].y), "+v"(wr[5].z), "+v"(wr[5].w),
                    "+v"(wr[6].x), "+v"(wr[6].y), "+v"(wr[6].z), "+v"(wr[6].w),
                    "+v"(wr[7].x), "+v"(wr[7].y), "+v"(wr[7].z), "+v"(wr[7].w));

  // --- zx FIFO depth 2 (lane 0 of each wave; 1 scalar per wave per step) ---
  float z0 = 0.0f, z1 = 0.0f;
  if (lane == 0) {
    z0 = zx[(long long)1 * DH + row];
    z1 = zx[(long long)2 * DH + row];
  }

  for (int t = 1; t < TSEQ; ++t) {
    float zn = 0.0f;
    if (lane == 0) {
      const int tp = (t + 2 < TSEQ) ? t + 2 : TSEQ - 1;
      zn = zx[(long long)tp * DH + row];
    }

    if (w < 2) {
      // ---- poller wave: own 16 contiguous h columns ----
      const int c0 = w * 1024 + lane * 16;
      float v[16];
      if (t == 1) {
#pragma unroll
        for (int k = 0; k < 4; ++k) {
          float4 f4 = *(const float4*)(features + c0 + 4 * k);
          v[4 * k]     = f4.x;
          v[4 * k + 1] = f4.y;
          v[4 * k + 2] = f4.z;
          v[4 * k + 3] = f4.w;
        }
      } else {
        const unsigned long long* hrow =
            (const unsigned long long*)(out + (long long)(t - 1) * DH + c0);
        unsigned long long u[8];
        for (;;) {
          unsigned long long m = 0ull;
#pragma unroll
          for (int k = 0; k < 8; ++k) {
            u[k] = __hip_atomic_load(hrow + k, __ATOMIC_RELAXED,
                                     __HIP_MEMORY_SCOPE_AGENT);
            m |= u[k];
          }
          if ((m & 0x8000000080000000ull) == 0ull) break;
          __builtin_amdgcn_s_sleep(1);
        }
#pragma unroll
        for (int k = 0; k < 8; ++k) {
          v[2 * k]     = __uint_as_float((unsigned int)u[k]);
          v[2 * k + 1] = __uint_as_float((unsigned int)(u[k] >> 32));
        }
      }
      // swizzled LDS write: granules g0..g0+3
      const int g0 = c0 >> 2;
#pragma unroll
      for (int k = 0; k < 4; ++k) {
        float4 h4;
        h4.x = v[4 * k]; h4.y = v[4 * k + 1];
        h4.z = v[4 * k + 2]; h4.w = v[4 * k + 3];
        *(float4*)&hb[t & 1][4 * swzg(g0 + k)] = h4;
      }
    }
    __syncthreads();

    // ---- all 16 waves: own row over own 32 cols (swizzled LDS reads) ----
    float a0 = 0.f, a1 = 0.f, a2 = 0.f, a3 = 0.f;
#pragma unroll
    for (int k = 0; k < 8; ++k) {
      float4 h4 = *(const float4*)&hb[t & 1][4 * swzg(8 * lane + k)];
      a0 += wr[k].x * h4.x;
      a1 += wr[k].y * h4.y;
      a2 += wr[k].z * h4.z;
      a3 += wr[k].w * h4.w;
    }
    float s = (a0 + a1) + (a2 + a3);
    s += __shfl_xor(s, 1, 64);
    s += __shfl_xor(s, 2, 64);
    s += __shfl_xor(s, 4, 64);
    s += __shfl_xor(s, 8, 64);
    s += __shfl_xor(s, 16, 64);
    s += __shfl_xor(s, 32, 64);

    if (lane == 0) {
      float h = 1.0f / (1.0f + __expf(-(s + z0)));
      __hip_atomic_store((unsigned int*)(out + (long long)t * DH + row),
                         __float_as_uint(h), __ATOMIC_RELAXED,
                         __HIP_MEMORY_SCOPE_AGENT);
    }
    z0 = z1;
    z1 = zn;
  }
}

// ---------------------------------------------------------------------------
// Kernel 2-fallback (ws too small): round-4/6 verified sentinel-spin kernel.
// ---------------------------------------------------------------------------
__global__ __launch_bounds__(512, 1) void seq_kernel_fb(
    const float* __restrict__ features, const float* __restrict__ caption,
    const float* __restrict__ W_h, const float* __restrict__ b_h,
    float* __restrict__ out) {
  const int tid  = threadIdx.x;
  const int i    = tid & 255;
  const int part = tid >> 8;
  const int rbase = blockIdx.x * ROWS;
  const int lane = tid & 63;
  const int wid  = tid >> 6;

  __shared__ float wlds[512 * 64];
  __shared__ float red[8][ROWS];

  const int swz = (tid & 7) << 2;
#pragma unroll
  for (int r = 0; r < ROWS; ++r) {
    const float* wrow = W_h + (long long)(rbase + r) * DCAT + part * DH;
#pragma unroll
    for (int q = 0; q < 4; ++q) {
      float2 wv = *(const float2*)(wrow + q * 512 + i * 2);
      const int lofs = r * 8 + q * 2;
      *(float2*)&wlds[tid * 64 + (((lofs & ~3) ^ swz) | (lofs & 3))] = wv;
    }
  }
  const float bias = (tid < ROWS) ? b_h[rbase + tid] : 0.0f;
  __syncthreads();

  float an[8];
  if (part == 0) {
#pragma unroll
    for (int q = 0; q < 4; ++q) {
      float2 xv = *(const float2*)(caption + q * 512 + i * 2);
      an[2 * q]     = xv.x;
      an[2 * q + 1] = xv.y;
    }
  }

  for (int t = 1; t < TSEQ; ++t) {
    float4 wr0[ROWS], wr1[ROWS];
#pragma unroll
    for (int r = 0; r < ROWS; ++r) {
      wr0[r] = *(const float4*)&wlds[tid * 64 + ((r * 8) ^ swz)];
      wr1[r] = *(const float4*)&wlds[tid * 64 + ((r * 8 + 4) ^ swz)];
    }

    float a[8];
    if (part == 0) {
#pragma unroll
      for (int j = 0; j < 8; ++j) a[j] = an[j];
      const float* xn = caption + (long long)t * DH;
#pragma unroll
      for (int q = 0; q < 4; ++q) {
        float2 xv = *(const float2*)(xn + q * 512 + i * 2);
        an[2 * q]     = xv.x;
        an[2 * q + 1] = xv.y;
      }
    } else if (t == 1) {
#pragma unroll
      for (int q = 0; q < 4; ++q) {
        float2 xv = *(const float2*)(features + q * 512 + i * 2);
        a[2 * q]     = xv.x;
        a[2 * q + 1] = xv.y;
      }
    } else {
      const unsigned long long* hrow =
          (const unsigned long long*)(out + (long long)(t - 1) * DH);
      unsigned long long v[4];
      for (;;) {
        unsigned long long m = 0ull;
#pragma unroll
        for (int q = 0; q < 4; ++q) {
          v[q] = __hip_atomic_load(hrow + q * 256 + i, __ATOMIC_RELAXED,
                                   __HIP_MEMORY_SCOPE_AGENT);
          m |= v[q];
        }
        if ((m & 0x8000000080000000ull) == 0ull) break;
        __builtin_amdgcn_s_sleep(1);
      }
#pragma unroll
      for (int q = 0; q < 4; ++q) {
        a[2 * q]     = __uint_as_float((unsigned int)v[q]);
        a[2 * q + 1] = __uint_as_float((unsigned int)(v[q] >> 32));
      }
    }

    float acc[ROWS];
#pragma unroll
    for (int r = 0; r < ROWS; ++r) {
      acc[r] = wr0[r].x * a[0] + wr0[r].y * a[1] + wr0[r].z * a[2] +
               wr0[r].w * a[3] + wr1[r].x * a[4] + wr1[r].y * a[5] +
               wr1[r].z * a[6] + wr1[r].w * a[7];
    }

    float vv[8];
#pragma unroll
    for (int r = 0; r < ROWS; ++r) vv[r] = acc[r];
    {
      const bool up = lane & 1;
#pragma unroll
      for (int j = 0; j < 4; ++j) {
        float send  = up ? vv[j] : vv[j + 4];
        float other = __shfl_xor(send, 1, 64);
        vv[j] = (up ? vv[j + 4] : vv[j]) + other;
      }
    }
    {
      const bool up = lane & 2;
#pragma unroll
      for (int j = 0; j < 2; ++j) {
        float send  = up ? vv[j] : vv[j + 2];
        float other = __shfl_xor(send, 2, 64);
        vv[j] = (up ? vv[j + 2] : vv[j]) + other;
      }
    }
    {
      const bool up = lane & 4;
      float send  = up ? vv[0] : vv[1];
      float other = __shfl_xor(send, 4, 64);
      vv[0] = (up ? vv[1] : vv[0]) + other;
    }
    float v = vv[0];
    v += __shfl_xor(v, 8, 64);
    v += __shfl_xor(v, 16, 64);
    v += __shfl_xor(v, 32, 64);
    if (lane < 8) {
      const int row = ((lane & 1) << 2) | (lane & 2) | ((lane >> 2) & 1);
      red[wid][row] = v;
    }
    __syncthreads();

    if (tid < ROWS) {
      float z = bias;
#pragma unroll
      for (int wv2 = 0; wv2 < 8; ++wv2) z += red[wv2][tid];
      float h = 1.0f / (1.0f + __expf(-z));
      __hip_atomic_store((unsigned int*)(out + (long long)t * DH + rbase + tid),
                         __float_as_uint(h), __ATOMIC_RELAXED,
                         __HIP_MEMORY_SCOPE_AGENT);
    }
    __syncthreads();
  }
}

// ---------------------------------------------------------------------------
// Kernel 3: output projection via bf16 MFMA, IN PLACE on d_out (verified).
// ---------------------------------------------------------------------------
__global__ __launch_bounds__(256, 1) void out_mfma_kernel(
    float* __restrict__ out, const float* __restrict__ W_o,
    const float* __restrict__ b_o, const float* __restrict__ caption) {
  __shared__ __align__(16) short hs[R3 * 2048];  // exactly 128 KiB
  const int tid  = threadIdx.x;
  const int lane = tid & 63;
  const int wv   = tid >> 6;
  const long long t0 = (long long)blockIdx.x * R3;
  const int r16  = lane & 15;
  const int kgrp = (lane >> 4) * 8;

  for (int idx = tid; idx < R3 * 256; idx += 256) {
    const int row = idx >> 8;
    const int c8  = idx & 255;
    const float* src = out + (t0 + row) * DH + c8 * 8;
    float4 va = *(const float4*)src;
    float4 vb = *(const float4*)(src + 4);
    bf16x8 h8;
    h8[0] = f2bf(va.x); h8[1] = f2bf(va.y); h8[2] = f2bf(va.z); h8[3] = f2bf(va.w);
    h8[4] = f2bf(vb.x); h8[5] = f2bf(vb.y); h8[6] = f2bf(vb.z); h8[7] = f2bf(vb.w);
    *(bf16x8*)&hs[row * 2048 + ((c8 * 8) ^ ((row & 7) << 3))] = h8;
  }
  __syncthreads();

  const int sw0 = (r16 & 7) << 3;

  for (int half = 0; half < 4; ++half) {
    const int n0 = wv * 512 + half * 128;
    f32x4 acc0[8], acc1[8];
#pragma unroll
    for (int j = 0; j < 8; ++j) {
      acc0[j] = (f32x4){0.f, 0.f, 0.f, 0.f};
      acc1[j] = (f32x4){0.f, 0.f, 0.f, 0.f};
    }
    for (int k0 = 0; k0 < DH; k0 += 32) {
      const int kofs = (k0 + kgrp) ^ sw0;
      bf16x8 a0 = *(const bf16x8*)&hs[r16 * 2048 + kofs];
      bf16x8 a1 = *(const bf16x8*)&hs[(16 + r16) * 2048 + kofs];
#pragma unroll
      for (int j = 0; j < 8; ++j) {
        const float* wp =
            W_o + (long long)(n0 + j * 16 + r16) * DH + k0 + kgrp;
        float4 wa = *(const float4*)wp;
        float4 wb = *(const float4*)(wp + 4);
        bf16x8 bfr;
        bfr[0] = f2bf(wa.x); bfr[1] = f2bf(wa.y);
        bfr[2] = f2bf(wa.z); bfr[3] = f2bf(wa.w);
        bfr[4] = f2bf(wb.x); bfr[5] = f2bf(wb.y);
        bfr[6] = f2bf(wb.z); bfr[7] = f2bf(wb.w);
        acc0[j] = __builtin_amdgcn_mfma_f32_16x16x32_bf16(a0, bfr, acc0[j], 0, 0, 0);
        acc1[j] = __builtin_amdgcn_mfma_f32_16x16x32_bf16(a1, bfr, acc1[j], 0, 0, 0);
      }
    }
#pragma unroll
    for (int j = 0; j < 8; ++j) {
      const int n = n0 + j * 16 + r16;
      const float bo = b_o[n];
#pragma unroll
      for (int r = 0; r < 4; ++r) {
        const long long row0 = t0 + (lane >> 4) * 4 + r;
        float v0 = 1.0f / (1.0f + __expf(-(acc0[j][r] + bo)));
        if (row0 == 0) v0 = caption[n];  // output[0] = caption[0]
        out[row0 * DH + n] = v0;
        const long long row1 = t0 + 16 + (lane >> 4) * 4 + r;
        float v1 = 1.0f / (1.0f + __expf(-(acc1[j][r] + bo)));
        out[row1 * DH + n] = v1;
      }
    }
  }
}

// ---------------------------------------------------------------------------
extern "C" void kernel_launch(void* const* d_in, const int* in_sizes, int n_in,
                              void* d_out, int out_size, void* d_ws,
                              size_t ws_size, hipStream_t stream) {
  const float* features = (const float*)d_in[0];
  const float* caption  = (const float*)d_in[1];
  const float* W_h      = (const float*)d_in[2];
  const float* b_h      = (const float*)d_in[3];
  const float* W_o      = (const float*)d_in[4];
  const float* b_o      = (const float*)d_in[5];
  float* out = (float*)d_out;

  hipLaunchKernelGGL(init_sentinel_kernel, dim3(2048), dim3(256), 0, stream,
                     out);

  const size_t zx_bytes = (size_t)TSEQ * DH * sizeof(float);
  if (ws_size >= zx_bytes) {
    float* zx = (float*)d_ws;
    hipLaunchKernelGGL(zx_mfma_kernel, dim3(TSEQ / R3), dim3(256), 0, stream,
                       zx, caption, W_h, b_h);
    hipLaunchKernelGGL(seq_kernel, dim3(NWG), dim3(1024), 0, stream,
                       features, zx, W_h, out);
  } else {
    hipLaunchKernelGGL(seq_kernel_fb, dim3(DH / ROWS), dim3(512), 0, stream,
                       features, caption, W_h, b_h, out);
  }

  hipLaunchKernelGGL(out_mfma_kernel, dim3(TSEQ / R3), dim3(256), 0, stream,
                     out, W_o, b_o, caption);
}

// Round 11
// 12747.860 us; speedup vs baseline: 1.7205x; 1.7205x over previous
//
#include <hip/hip_runtime.h>

#define TSEQ 8192
#define DH   2048
#define DCAT 4096
#define ROWS 8      // hidden rows per seq workgroup (2048 / 256 WGs)
#define R3   32     // time rows per MFMA workgroup
#define WSTRIDE 68  // per-thread LDS weight block stride (floats); 68*4B=272B
                    // == stride-4-dword bank pattern -> conflict-free b128

typedef __attribute__((ext_vector_type(8))) short bf16x8;
typedef __attribute__((ext_vector_type(4))) float f32x4;

__device__ inline short f2bf(float f) {  // RNE float->bf16
  unsigned int u = __float_as_uint(f);
  unsigned int r = (u + 0x7fffu + ((u >> 16) & 1u)) >> 16;
  return (short)r;
}

// ---------------------------------------------------------------------------
// Kernel 1: sentinel-init rows 1..8191 of d_out (h exchange buffer).
// Valid h values are sigmoid outputs (sign bit 0); sentinel -1.0f has sign 1.
// Runs every launch (harness does not re-poison between replays).
// ---------------------------------------------------------------------------
__global__ void init_sentinel_kernel(float* __restrict__ out) {
  const long long n4 = ((long long)(TSEQ - 1) * DH) / 4;  // rows 1..8191
  float4* p = (float4*)(out + DH);
  float4 s;
  s.x = s.y = s.z = s.w = -1.0f;
  const long long stride = (long long)gridDim.x * blockDim.x;
  for (long long i = (long long)blockIdx.x * blockDim.x + threadIdx.x; i < n4;
       i += stride)
    p[i] = s;
}

// ---------------------------------------------------------------------------
// Kernel 2: persistent sequential RNN — the measured-best structure (round-4
// bench: 1.73us/step DESPITE 1.07e9 bank conflicts; every later redesign
// regressed => in this structure all compute overlaps the spin and the
// rendezvous is the critical path). Only change vs that kernel: per-thread
// LDS weight blocks are padded to stride 68 floats, which puts lane l's
// ds_read_b128 at bank 4*(l%8) — the canonical conflict-free pattern — so
// SQ_LDS_BANK_CONFLICT should drop 1.07e9 -> ~0 with nothing else perturbed.
//
// Structure: 256 WGs x 512 threads. WG g owns hidden rows [8g, 8g+8).
// Threads 0..255 (x half) stream caption rows one step ahead (off critical
// path); threads 256..511 (h half) spin on agent-scope 8B loads of d_out
// row t-1, columns spread 2KB apart (4 lines/thread), sign-bit ready flag,
// s_sleep(1) backoff. Two barriers/step; folded wave reduce; serial 8-lane
// tail adds bias, sigmoid, agent-scope store publishes h[t].
// ---------------------------------------------------------------------------
__global__ __launch_bounds__(512, 1) void seq_kernel(
    const float* __restrict__ features, const float* __restrict__ caption,
    const float* __restrict__ W_h, const float* __restrict__ b_h,
    float* __restrict__ out) {
  const int tid  = threadIdx.x;
  const int i    = tid & 255;
  const int part = tid >> 8;
  const int rbase = blockIdx.x * ROWS;
  const int lane = tid & 63;
  const int wid  = tid >> 6;

  __shared__ float wlds[512 * WSTRIDE];   // 139264 B
  __shared__ float red[8][ROWS];

  // --- stage weights: thread's 64-float block, linear layout, stride 68 ---
#pragma unroll
  for (int r = 0; r < ROWS; ++r) {
    const float* wrow = W_h + (long long)(rbase + r) * DCAT + part * DH;
#pragma unroll
    for (int q = 0; q < 4; ++q) {
      float2 wv = *(const float2*)(wrow + q * 512 + i * 2);
      *(float2*)&wlds[tid * WSTRIDE + r * 8 + q * 2] = wv;
    }
  }
  const float bias = (tid < ROWS) ? b_h[rbase + tid] : 0.0f;
  __syncthreads();

  // x-half: preload caption row 0 (consumed at t=1)
  float an[8];
  if (part == 0) {
#pragma unroll
    for (int q = 0; q < 4; ++q) {
      float2 xv = *(const float2*)(caption + q * 512 + i * 2);
      an[2 * q]     = xv.x;
      an[2 * q + 1] = xv.y;
    }
  }

  for (int t = 1; t < TSEQ; ++t) {
    // issue weight ds_reads first (latency hides under the spin)
    float4 wr0[ROWS], wr1[ROWS];
#pragma unroll
    for (int r = 0; r < ROWS; ++r) {
      wr0[r] = *(const float4*)&wlds[tid * WSTRIDE + r * 8];
      wr1[r] = *(const float4*)&wlds[tid * WSTRIDE + r * 8 + 4];
    }

    float a[8];
    if (part == 0) {
      // consume prefetched row t-1; issue prefetch of row t (for t+1).
#pragma unroll
      for (int j = 0; j < 8; ++j) a[j] = an[j];
      const float* xn = caption + (long long)t * DH;
#pragma unroll
      for (int q = 0; q < 4; ++q) {
        float2 xv = *(const float2*)(xn + q * 512 + i * 2);
        an[2 * q]     = xv.x;
        an[2 * q + 1] = xv.y;
      }
    } else if (t == 1) {
      // h0 = features (input, no wait)
#pragma unroll
      for (int q = 0; q < 4; ++q) {
        float2 xv = *(const float2*)(features + q * 512 + i * 2);
        a[2 * q]     = xv.x;
        a[2 * q + 1] = xv.y;
      }
    } else {
      // spin on h_{t-1}: agent-scope 8B loads, columns spread 2KB apart
      const unsigned long long* hrow =
          (const unsigned long long*)(out + (long long)(t - 1) * DH);
      unsigned long long v[4];
      for (;;) {
        unsigned long long m = 0ull;
#pragma unroll
        for (int q = 0; q < 4; ++q) {
          v[q] = __hip_atomic_load(hrow + q * 256 + i, __ATOMIC_RELAXED,
                                   __HIP_MEMORY_SCOPE_AGENT);
          m |= v[q];
        }
        if ((m & 0x8000000080000000ull) == 0ull) break;
        __builtin_amdgcn_s_sleep(1);
      }
#pragma unroll
      for (int q = 0; q < 4; ++q) {
        a[2 * q]     = __uint_as_float((unsigned int)v[q]);
        a[2 * q + 1] = __uint_as_float((unsigned int)(v[q] >> 32));
      }
    }

    // --- per-thread partials: 8 rows x 8 cols ---
    float acc[ROWS];
#pragma unroll
    for (int r = 0; r < ROWS; ++r) {
      acc[r] = wr0[r].x * a[0] + wr0[r].y * a[1] + wr0[r].z * a[2] +
               wr0[r].w * a[3] + wr1[r].x * a[4] + wr1[r].y * a[5] +
               wr1[r].z * a[6] + wr1[r].w * a[7];
    }

    // --- folded wave reduction (verified rounds 1-10) ---
    float vv[8];
#pragma unroll
    for (int r = 0; r < ROWS; ++r) vv[r] = acc[r];
    {
      const bool up = lane & 1;
#pragma unroll
      for (int j = 0; j < 4; ++j) {
        float send  = up ? vv[j] : vv[j + 4];
        float other = __shfl_xor(send, 1, 64);
        vv[j] = (up ? vv[j + 4] : vv[j]) + other;
      }
    }
    {
      const bool up = lane & 2;
#pragma unroll
      for (int j = 0; j < 2; ++j) {
        float send  = up ? vv[j] : vv[j + 2];
        float other = __shfl_xor(send, 2, 64);
        vv[j] = (up ? vv[j + 2] : vv[j]) + other;
      }
    }
    {
      const bool up = lane & 4;
      float send  = up ? vv[0] : vv[1];
      float other = __shfl_xor(send, 4, 64);
      vv[0] = (up ? vv[1] : vv[0]) + other;
    }
    float v = vv[0];
    v += __shfl_xor(v, 8, 64);
    v += __shfl_xor(v, 16, 64);
    v += __shfl_xor(v, 32, 64);
    if (lane < 8) {
      const int row = ((lane & 1) << 2) | (lane & 2) | ((lane >> 2) & 1);
      red[wid][row] = v;
    }
    __syncthreads();

    if (tid < ROWS) {
      float z = bias;
#pragma unroll
      for (int wv2 = 0; wv2 < 8; ++wv2) z += red[wv2][tid];
      float h = 1.0f / (1.0f + __expf(-z));
      __hip_atomic_store((unsigned int*)(out + (long long)t * DH + rbase + tid),
                         __float_as_uint(h), __ATOMIC_RELAXED,
                         __HIP_MEMORY_SCOPE_AGENT);
    }
    __syncthreads();
  }
}

// ---------------------------------------------------------------------------
// Kernel 3: output projection via bf16 MFMA, IN PLACE on d_out (verified).
// WG owns R3=32 time-rows; stages them as bf16 in LDS (128 KB, XOR-swizzled
// both sides); W_o B-frags converted f32->bf16 on the fly. Row 0=caption[0].
// ---------------------------------------------------------------------------
__global__ __launch_bounds__(256, 1) void out_mfma_kernel(
    float* __restrict__ out, const float* __restrict__ W_o,
    const float* __restrict__ b_o, const float* __restrict__ caption) {
  __shared__ __align__(16) short hs[R3 * 2048];  // exactly 128 KiB
  const int tid  = threadIdx.x;
  const int lane = tid & 63;
  const int wv   = tid >> 6;
  const long long t0 = (long long)blockIdx.x * R3;
  const int r16  = lane & 15;
  const int kgrp = (lane >> 4) * 8;

  for (int idx = tid; idx < R3 * 256; idx += 256) {
    const int row = idx >> 8;
    const int c8  = idx & 255;
    const float* src = out + (t0 + row) * DH + c8 * 8;
    float4 va = *(const float4*)src;
    float4 vb = *(const float4*)(src + 4);
    bf16x8 h8;
    h8[0] = f2bf(va.x); h8[1] = f2bf(va.y); h8[2] = f2bf(va.z); h8[3] = f2bf(va.w);
    h8[4] = f2bf(vb.x); h8[5] = f2bf(vb.y); h8[6] = f2bf(vb.z); h8[7] = f2bf(vb.w);
    *(bf16x8*)&hs[row * 2048 + ((c8 * 8) ^ ((row & 7) << 3))] = h8;
  }
  __syncthreads();

  const int sw0 = (r16 & 7) << 3;

  for (int half = 0; half < 4; ++half) {
    const int n0 = wv * 512 + half * 128;
    f32x4 acc0[8], acc1[8];
#pragma unroll
    for (int j = 0; j < 8; ++j) {
      acc0[j] = (f32x4){0.f, 0.f, 0.f, 0.f};
      acc1[j] = (f32x4){0.f, 0.f, 0.f, 0.f};
    }
    for (int k0 = 0; k0 < DH; k0 += 32) {
      const int kofs = (k0 + kgrp) ^ sw0;
      bf16x8 a0 = *(const bf16x8*)&hs[r16 * 2048 + kofs];
      bf16x8 a1 = *(const bf16x8*)&hs[(16 + r16) * 2048 + kofs];
#pragma unroll
      for (int j = 0; j < 8; ++j) {
        const float* wp =
            W_o + (long long)(n0 + j * 16 + r16) * DH + k0 + kgrp;
        float4 wa = *(const float4*)wp;
        float4 wb = *(const float4*)(wp + 4);
        bf16x8 bfr;
        bfr[0] = f2bf(wa.x); bfr[1] = f2bf(wa.y);
        bfr[2] = f2bf(wa.z); bfr[3] = f2bf(wa.w);
        bfr[4] = f2bf(wb.x); bfr[5] = f2bf(wb.y);
        bfr[6] = f2bf(wb.z); bfr[7] = f2bf(wb.w);
        acc0[j] = __builtin_amdgcn_mfma_f32_16x16x32_bf16(a0, bfr, acc0[j], 0, 0, 0);
        acc1[j] = __builtin_amdgcn_mfma_f32_16x16x32_bf16(a1, bfr, acc1[j], 0, 0, 0);
      }
    }
#pragma unroll
    for (int j = 0; j < 8; ++j) {
      const int n = n0 + j * 16 + r16;
      const float bo = b_o[n];
#pragma unroll
      for (int r = 0; r < 4; ++r) {
        const long long row0 = t0 + (lane >> 4) * 4 + r;
        float v0 = 1.0f / (1.0f + __expf(-(acc0[j][r] + bo)));
        if (row0 == 0) v0 = caption[n];  // output[0] = caption[0]
        out[row0 * DH + n] = v0;
        const long long row1 = t0 + 16 + (lane >> 4) * 4 + r;
        float v1 = 1.0f / (1.0f + __expf(-(acc1[j][r] + bo)));
        out[row1 * DH + n] = v1;
      }
    }
  }
}

// ---------------------------------------------------------------------------
extern "C" void kernel_launch(void* const* d_in, const int* in_sizes, int n_in,
                              void* d_out, int out_size, void* d_ws,
                              size_t ws_size, hipStream_t stream) {
  const float* features = (const float*)d_in[0];
  const float* caption  = (const float*)d_in[1];
  const float* W_h      = (const float*)d_in[2];
  const float* b_h      = (const float*)d_in[3];
  const float* W_o      = (const float*)d_in[4];
  const float* b_o      = (const float*)d_in[5];
  float* out = (float*)d_out;

  hipLaunchKernelGGL(init_sentinel_kernel, dim3(2048), dim3(256), 0, stream,
                     out);
  hipLaunchKernelGGL(seq_kernel, dim3(DH / ROWS), dim3(512), 0, stream,
                     features, caption, W_h, b_h, out);
  hipLaunchKernelGGL(out_mfma_kernel, dim3(TSEQ / R3), dim3(256), 0, stream,
                     out, W_o, b_o, caption);
}